// Round 1
// baseline (3094.382 us; speedup 1.0000x reference)
//
#include <hip/hip_runtime.h>
#include <math.h>

#define NTY 5
#define NET 10
#define NTOT 307000
#define ETOT 6800000
#define GDIM 1024
#define PDIM 768

// ---- compile-time problem tables ----
static const int kNS[NET]  = {5000,5000,5000,2000,2000,50000,100000,150000,50000,100000};
static const int kND[NET]  = {50000,100000,150000,50000,100000,5000,5000,5000,2000,2000};
static const int kEC[NET]  = {500000,1000000,1000000,300000,600000,500000,1000000,1000000,300000,600000};
static const int kSRCT[NET]= {0,0,0,4,4,1,2,3,1,2};
static const int kDSTT[NET]= {1,2,3,1,2,0,0,0,4,4};
static const int kNT[NTY]  = {5000,50000,100000,150000,2000};
static const int kTOFF[NTY]= {0,5000,55000,155000,305000};
static const int kEB[NET+1]= {0,500000,1500000,2500000,2800000,3400000,3900000,4900000,5900000,6200000,6800000};
static const int kRB[NET+1]= {0,50000,150000,300000,350000,450000,455000,460000,465000,467000,469000};
static const int kBB[NET+1]= {0,49,147,294,343,441,446,451,456,458,460};

struct EdgeTab {
  const int* ei[NET];
  int ebase[NET+1];
  int obase[NET];
  int rbase[NET+1];
};
struct ScanTab {
  int bbase[NET+1];
  int cbase[NET];
  int obase[NET];
  int pbase[NET];
  int nd[NET];
  int ec[NET];
};
struct SdTab {
  const float* x[NET];
  int rbase[NET+1];
  int K;
};
struct BiasTab { int dstt[NET]; };
struct PoolTab { const int* batch[NTY]; const float* x[NTY]; int nt[NTY]; };

// ---------------- CSR build ----------------
__global__ __launch_bounds__(256) void k_hist(EdgeTab t, int* __restrict__ counts) {
  int gid = blockIdx.x*256 + threadIdx.x;
  if (gid >= t.ebase[NET]) return;
  int et = 0;
  #pragma unroll
  for (int i=0;i<NET;i++) if (gid >= t.ebase[i+1]) et = i+1;
  int e = gid - t.ebase[et];
  int E = t.ebase[et+1]-t.ebase[et];
  int dst = t.ei[et][E + e];
  atomicAdd(&counts[t.rbase[et] + dst], 1);
}

__global__ __launch_bounds__(256) void k_scan1(ScanTab t, const int* __restrict__ counts,
                                               int* __restrict__ offs, int* __restrict__ partials) {
  __shared__ int sd[256];
  int b = blockIdx.x;
  int et = 0;
  #pragma unroll
  for (int i=0;i<NET;i++) if (b >= t.bbase[i+1]) et = i+1;
  int lb = b - t.bbase[et];
  int n = t.nd[et];
  const int* cin = counts + t.cbase[et];
  int* oo = offs + t.obase[et];
  int tid = threadIdx.x;
  int base = lb*1024 + tid*4;
  int v0 = (base+0<n)?cin[base+0]:0;
  int v1 = (base+1<n)?cin[base+1]:0;
  int v2 = (base+2<n)?cin[base+2]:0;
  int v3 = (base+3<n)?cin[base+3]:0;
  int tsum = v0+v1+v2+v3;
  sd[tid]=tsum; __syncthreads();
  for (int off=1; off<256; off<<=1) {
    int x = (tid>=off)? sd[tid-off] : 0;
    __syncthreads();
    sd[tid] += x;
    __syncthreads();
  }
  int run = sd[tid]-tsum;
  if (tid==255) partials[t.pbase[et]+lb]=sd[255];
  if (base+0<n){ oo[base+0]=run; run+=v0; }
  if (base+1<n){ oo[base+1]=run; run+=v1; }
  if (base+2<n){ oo[base+2]=run; run+=v2; }
  if (base+3<n){ oo[base+3]=run; }
}

__global__ __launch_bounds__(256) void k_scan2(ScanTab t, int* __restrict__ partials) {
  __shared__ int sd[256];
  int et = blockIdx.x;
  int nb = t.bbase[et+1]-t.bbase[et];
  int tid = threadIdx.x;
  int v = (tid<nb)? partials[t.pbase[et]+tid] : 0;
  sd[tid]=v; __syncthreads();
  for (int off=1; off<256; off<<=1) {
    int x=(tid>=off)?sd[tid-off]:0;
    __syncthreads();
    sd[tid]+=x;
    __syncthreads();
  }
  if (tid<nb) partials[t.pbase[et]+tid] = sd[tid]-v;
}

__global__ __launch_bounds__(256) void k_scan3(ScanTab t, int* __restrict__ offs,
                                               const int* __restrict__ partials) {
  int b = blockIdx.x;
  int et=0;
  #pragma unroll
  for (int i=0;i<NET;i++) if (b>=t.bbase[i+1]) et=i+1;
  int lb = b - t.bbase[et];
  int n = t.nd[et];
  int* oo = offs + t.obase[et];
  int add = partials[t.pbase[et]+lb];
  int tid = threadIdx.x;
  int base = lb*1024 + tid*4;
  #pragma unroll
  for (int j=0;j<4;j++) if (base+j<n) oo[base+j]+=add;
  if (lb==0 && tid==0) oo[n] = t.ec[et];
}

__global__ __launch_bounds__(256) void k_scatter(EdgeTab t, int* __restrict__ cursor, int* __restrict__ csr) {
  int gid = blockIdx.x*256 + threadIdx.x;
  if (gid >= t.ebase[NET]) return;
  int et=0;
  #pragma unroll
  for (int i=0;i<NET;i++) if (gid>=t.ebase[i+1]) et=i+1;
  int e = gid - t.ebase[et];
  int E = t.ebase[et+1]-t.ebase[et];
  int src = t.ei[et][e];
  int dst = t.ei[et][E+e];
  int pos = atomicAdd(&cursor[t.obase[et]+dst], 1);
  csr[t.ebase[et] + pos] = src;
}

// ---------------- per-layer ----------------
__global__ void k_bias(const float* __restrict__ b, BiasTab t, float* __restrict__ bsum) {
  int tid = threadIdx.x;            // 320 threads
  int ty = tid>>6, c = tid&63;
  float s = 0.f;
  #pragma unroll
  for (int i=0;i<NET;i++) if (t.dstt[i]==ty) s += b[i*64+c];
  bsum[tid]=s;
}

__global__ __launch_bounds__(256) void k_init(const float* __restrict__ bsum, float* __restrict__ xout) {
  long i = (long)blockIdx.x*256 + threadIdx.x;
  if (i >= (long)NTOT*64) return;
  int node = (int)(i>>6);
  int ty = (node>=5000) + (node>=55000) + (node>=155000) + (node>=305000);
  xout[i] = bsum[ty*64 + ((int)i&63)];
}

__global__ void k_wdst(const float* __restrict__ Wd, const float* __restrict__ ad,
                       float* __restrict__ wv, int K) {
  int et = blockIdx.x; int k = threadIdx.x;
  if (k>=K) return;
  const float* W = Wd + (long)et*K*64;
  const float* a = ad + et*64;
  float s=0.f;
  #pragma unroll 8
  for (int c=0;c<64;c++) s += W[k*64+c]*a[c];
  wv[et*256+k]=s;
}

__global__ __launch_bounds__(256) void k_sdst(SdTab t, const float* __restrict__ wv_all,
                                              float* __restrict__ sdst) {
  int w = (blockIdx.x*256 + threadIdx.x)>>6;
  int lane = threadIdx.x & 63;
  if (w >= t.rbase[NET]) return;
  int et=0;
  #pragma unroll
  for (int i=0;i<NET;i++) if (w>=t.rbase[i+1]) et=i+1;
  int row = w - t.rbase[et];
  const float* x = t.x[et];
  const float* wv = wv_all + et*256;
  int K = t.K;
  float acc=0.f;
  for (int k=lane;k<K;k+=64) acc += x[(long)row*K + k]*wv[k];
  #pragma unroll
  for (int off=32;off;off>>=1) acc += __shfl_xor(acc, off);
  if (lane==0) sdst[t.rbase[et]+row]=acc;
}

__global__ __launch_bounds__(256) void k_gemm(
    const float* __restrict__ X, const float* __restrict__ W,
    const float* __restrict__ avec, float* __restrict__ HS,
    float* __restrict__ score, int Ns, int K)
{
  __shared__ float sX[64][68];
  __shared__ float sW[64][64];
  int tid = threadIdx.x;
  int row0 = blockIdx.x*64;
  int tr = tid>>4, tc = tid&15;
  float acc[4][4]={};
  for (int k0=0;k0<K;k0+=64){
    #pragma unroll
    for (int p=0;p<4;p++){
      int r = (tid>>4) + 16*p;
      int c = (tid&15)*4;
      int gr = row0 + r;
      float4 xv = make_float4(0.f,0.f,0.f,0.f);
      if (gr < Ns) xv = *(const float4*)(X + (long)gr*K + k0 + c);
      sX[r][c]=xv.x; sX[r][c+1]=xv.y; sX[r][c+2]=xv.z; sX[r][c+3]=xv.w;
      float4 wv4 = *(const float4*)(W + (long)(k0+r)*64 + c);
      *(float4*)&sW[r][c] = wv4;
    }
    __syncthreads();
    #pragma unroll 8
    for (int k=0;k<64;k++){
      float a0=sX[tr*4+0][k],a1=sX[tr*4+1][k],a2=sX[tr*4+2][k],a3=sX[tr*4+3][k];
      float4 b4 = *(const float4*)&sW[k][tc*4];
      acc[0][0]+=a0*b4.x; acc[0][1]+=a0*b4.y; acc[0][2]+=a0*b4.z; acc[0][3]+=a0*b4.w;
      acc[1][0]+=a1*b4.x; acc[1][1]+=a1*b4.y; acc[1][2]+=a1*b4.z; acc[1][3]+=a1*b4.w;
      acc[2][0]+=a2*b4.x; acc[2][1]+=a2*b4.y; acc[2][2]+=a2*b4.z; acc[2][3]+=a2*b4.w;
      acc[3][0]+=a3*b4.x; acc[3][1]+=a3*b4.y; acc[3][2]+=a3*b4.z; acc[3][3]+=a3*b4.w;
    }
    __syncthreads();
  }
  float a4[4];
  #pragma unroll
  for (int j=0;j<4;j++) a4[j]=avec[tc*4+j];
  #pragma unroll
  for (int i=0;i<4;i++){
    int r = row0 + tr*4 + i;
    if (r < Ns){
      float4 o; o.x=acc[i][0]; o.y=acc[i][1]; o.z=acc[i][2]; o.w=acc[i][3];
      *(float4*)(HS + (long)r*64 + tc*4) = o;
    }
    float sc = acc[i][0]*a4[0]+acc[i][1]*a4[1]+acc[i][2]*a4[2]+acc[i][3]*a4[3];
    #pragma unroll
    for (int off=1;off<16;off<<=1) sc += __shfl_xor(sc, off);
    if (tc==0 && r<Ns) score[r]=sc;
  }
}

__global__ __launch_bounds__(64) void k_agg(
    const float* __restrict__ HS, const float* __restrict__ ssrc,
    const float* __restrict__ sdst, const int* __restrict__ offs,
    const int* __restrict__ csr, float* __restrict__ xout)
{
  int d = blockIdx.x;
  int lane = threadIdx.x;
  int beg = offs[d], end = offs[d+1];
  if (beg==end) return;
  float sdv = sdst[d];
  float m = -3.0e38f;
  for (int e=beg+lane; e<end; e+=64){
    float l = ssrc[csr[e]] + sdv;
    l = (l>0.f)? l : 0.2f*l;
    m = fmaxf(m,l);
  }
  #pragma unroll
  for (int off=32; off; off>>=1) m = fmaxf(m, __shfl_xor(m, off));
  float den=0.f, acc=0.f;
  for (int e=beg; e<end; ++e){
    int s = csr[e];
    float l = ssrc[s]+sdv; l=(l>0.f)?l:0.2f*l;
    float ex = __expf(l-m);
    den += ex;
    acc += ex * HS[(long)s*64 + lane];
  }
  xout[(long)d*64+lane] += acc/(den+1e-16f);
}

__global__ __launch_bounds__(256) void k_relu(float* __restrict__ x, long n) {
  long i = ((long)blockIdx.x*256+threadIdx.x)*4;
  if (i+3 < n) {
    float4 v = *(float4*)(x+i);
    v.x=fmaxf(v.x,0.f); v.y=fmaxf(v.y,0.f); v.z=fmaxf(v.z,0.f); v.w=fmaxf(v.w,0.f);
    *(float4*)(x+i)=v;
  } else {
    for (long j=i;j<n;j++) x[j]=fmaxf(x[j],0.f);
  }
}

// ---------------- pooling + head ----------------
__global__ __launch_bounds__(64) void k_pool(PoolTab t, float* __restrict__ pooled) {
  int g = blockIdx.x; int ty = blockIdx.y; int lane = threadIdx.x;
  const int* batch = t.batch[ty];
  int n = t.nt[ty];
  int lo=0, hi=0;
  if (lane==0){
    int a=0,b2=n;
    while(a<b2){int mm=(a+b2)>>1; if (batch[mm]<g) a=mm+1; else b2=mm;}
    lo=a;
    a=lo; b2=n;
    while(a<b2){int mm=(a+b2)>>1; if (batch[mm]<g+1) a=mm+1; else b2=mm;}
    hi=a;
  }
  lo=__shfl(lo,0); hi=__shfl(hi,0);
  const float* x = t.x[ty];
  float acc=0.f;
  for (int i=lo;i<hi;i++) acc += x[(long)i*64+lane];
  int cnt = hi-lo;
  pooled[(long)g*320 + ty*64 + lane] = acc / (float)(cnt>0?cnt:1);
}

__global__ __launch_bounds__(256) void k_final(
    const float* __restrict__ pooled, const float* __restrict__ post,
    const float* __restrict__ Wlin, const float* __restrict__ blin,
    float* __restrict__ out)
{
  int w = (blockIdx.x*256+threadIdx.x)>>6;
  int lane = threadIdx.x&63;
  if (w>=GDIM) return;
  float a0=0.f,a1=0.f;
  for (int k=lane;k<320+PDIM;k+=64){
    float v = (k<320) ? pooled[(long)w*320+k] : post[(long)w*PDIM + (k-320)];
    a0 += v*Wlin[k*2];
    a1 += v*Wlin[k*2+1];
  }
  #pragma unroll
  for (int off=32;off;off>>=1){ a0+=__shfl_xor(a0,off); a1+=__shfl_xor(a1,off); }
  if (lane==0){
    float z0=a0+blin[0], z1=a1+blin[1];
    z0=fmaxf(z0,0.f); z1=fmaxf(z1,0.f);
    float mm=fmaxf(z0,z1);
    float e0=__expf(z0-mm), e1=__expf(z1-mm);
    float inv = 1.f/(e0+e1);
    out[w*2+0]=e0*inv; out[w*2+1]=e1*inv;
  }
}

extern "C" void kernel_launch(void* const* d_in, const int* in_sizes, int n_in,
                              void* d_out, int out_size, void* d_ws, size_t ws_size,
                              hipStream_t stream) {
  (void)in_sizes; (void)n_in; (void)out_size; (void)ws_size;
  char* ws = (char*)d_ws;
  size_t off = 0;
  auto A = [&](size_t nbytes){ size_t o=off; off=(off+nbytes+255)&~((size_t)255); return o; };
  size_t xbuf1_o = A((size_t)NTOT*64*4);
  size_t xbuf2_o = A((size_t)NTOT*64*4);
  size_t hs_o    = A((size_t)150000*64*4);
  size_t csr_o   = A((size_t)ETOT*4);
  size_t offs_o  = A((size_t)469010*4);
  size_t cur_o   = A((size_t)469010*4);
  size_t cnt_o   = A((size_t)469000*4);
  size_t sdst_o  = A((size_t)469000*4);
  size_t ssrc_o  = A((size_t)150000*4);
  size_t pool_o  = A((size_t)GDIM*320*4);
  size_t wv_o    = A((size_t)NET*256*4);
  size_t bsum_o  = A((size_t)320*4);
  size_t part_o  = A((size_t)460*4);
  // total ~230 MB

  float* xbuf1 = (float*)(ws + xbuf1_o);
  float* xbuf2 = (float*)(ws + xbuf2_o);
  float* hsB   = (float*)(ws + hs_o);
  int*   csr   = (int*)(ws + csr_o);
  int*   offs  = (int*)(ws + offs_o);
  int*   cur   = (int*)(ws + cur_o);
  int*   cnts  = (int*)(ws + cnt_o);
  float* sdstA = (float*)(ws + sdst_o);
  float* ssrcB = (float*)(ws + ssrc_o);
  float* pooled= (float*)(ws + pool_o);
  float* wv    = (float*)(ws + wv_o);
  float* bsum  = (float*)(ws + bsum_o);
  int*   parts = (int*)(ws + part_o);

  int kOB[NET];
  for (int i=0;i<NET;i++) kOB[i] = kRB[i] + i;

  // ---- build CSR (once; edges identical for both layers) ----
  EdgeTab et;
  for (int i=0;i<NET;i++) et.ei[i] = (const int*)d_in[6+i];
  for (int i=0;i<=NET;i++) { et.ebase[i]=kEB[i]; et.rbase[i]=kRB[i]; }
  for (int i=0;i<NET;i++) et.obase[i]=kOB[i];

  ScanTab st;
  for (int i=0;i<=NET;i++) st.bbase[i]=kBB[i];
  for (int i=0;i<NET;i++) { st.cbase[i]=kRB[i]; st.obase[i]=kOB[i]; st.pbase[i]=kBB[i]; st.nd[i]=kND[i]; st.ec[i]=kEC[i]; }

  hipMemsetAsync(cnts, 0, (size_t)469000*4, stream);
  int egrid = (ETOT+255)/256;
  k_hist<<<egrid,256,0,stream>>>(et, cnts);
  k_scan1<<<kBB[NET],256,0,stream>>>(st, cnts, offs, parts);
  k_scan2<<<NET,256,0,stream>>>(st, parts);
  k_scan3<<<kBB[NET],256,0,stream>>>(st, offs, parts);
  hipMemcpyAsync(cur, offs, (size_t)469010*4, hipMemcpyDeviceToDevice, stream);
  k_scatter<<<egrid,256,0,stream>>>(et, cur, csr);

  BiasTab bt; for (int i=0;i<NET;i++) bt.dstt[i]=kDSTT[i];

  // ---- two GAT layers ----
  for (int l=0;l<2;l++){
    const float* Wsrc = (const float*)d_in[21+5*l];
    const float* Wdst = (const float*)d_in[22+5*l];
    const float* asrc = (const float*)d_in[23+5*l];
    const float* adst = (const float*)d_in[24+5*l];
    const float* bb   = (const float*)d_in[25+5*l];
    int K = l ? 64 : 256;
    const float* xin[NTY];
    float* xout = l ? xbuf2 : xbuf1;
    for (int t=0;t<NTY;t++)
      xin[t] = l ? (const float*)(xbuf1 + (long)kTOFF[t]*64) : (const float*)d_in[t];

    k_bias<<<1,320,0,stream>>>(bb, bt, bsum);
    k_init<<<(NTOT*64)/256,256,0,stream>>>(bsum, xout);
    k_wdst<<<NET,K,0,stream>>>(Wdst, adst, wv, K);

    SdTab sdt;
    for (int i=0;i<NET;i++) sdt.x[i]=xin[kDSTT[i]];
    for (int i=0;i<=NET;i++) sdt.rbase[i]=kRB[i];
    sdt.K = K;
    k_sdst<<<(469000/4),256,0,stream>>>(sdt, wv, sdstA);

    for (int e=0;e<NET;e++){
      int gx = (kNS[e]+63)/64;
      k_gemm<<<gx,256,0,stream>>>(xin[kSRCT[e]], Wsrc+(long)e*K*64, asrc+(long)e*64,
                                  hsB, ssrcB, kNS[e], K);
      k_agg<<<kND[e],64,0,stream>>>(hsB, ssrcB, sdstA + kRB[e], offs + kOB[e],
                                    csr + kEB[e], xout + (long)kTOFF[kDSTT[e]]*64);
    }
    k_relu<<<(NTOT*64/4+255)/256,256,0,stream>>>(xout, (long)NTOT*64);
  }

  // ---- pooling + head ----
  PoolTab pt;
  for (int t=0;t<NTY;t++){
    pt.batch[t] = (const int*)d_in[16+t];
    pt.x[t] = (const float*)(xbuf2 + (long)kTOFF[t]*64);
    pt.nt[t] = kNT[t];
  }
  dim3 pgrid(GDIM, NTY);
  k_pool<<<pgrid,64,0,stream>>>(pt, pooled);

  k_final<<<GDIM/4,256,0,stream>>>(pooled, (const float*)d_in[5],
                                   (const float*)d_in[31], (const float*)d_in[32],
                                   (float*)d_out);
}